// Round 6
// baseline (484.623 us; speedup 1.0000x reference)
//
#include <hip/hip_runtime.h>
#include <math.h>

typedef short v8s __attribute__((ext_vector_type(8)));
typedef short v4s __attribute__((ext_vector_type(4)));
typedef float v4f __attribute__((ext_vector_type(4)));
typedef unsigned long long ull;

constexpr int L_ = 2048;
constexpr int H_ = 2048;
constexpr float LOG2E = 1.4426950408889634f;
constexpr float QSCALE = 0.08838834764831845f * LOG2E; // 1/sqrt(128) * log2(e)

__device__ inline unsigned short f2bf(float f) {
    unsigned int u = __float_as_uint(f);
    u += 0x7fffu + ((u >> 16) & 1u);
    return (unsigned short)(u >> 16);
}

// pack two fp32 -> two bf16 in one u32 (round-half-up): 2 adds + 1 v_perm
__device__ inline unsigned int pk2bf(float lo, float hi) {
    unsigned int a = __float_as_uint(lo) + 0x8000u;
    unsigned int b = __float_as_uint(hi) + 0x8000u;
    return __builtin_amdgcn_perm(b, a, 0x07060302);  // {hi16(b), hi16(a)}
}

// async global->LDS, 16 bytes per lane; LDS dest = uniform base + lane*16B
__device__ inline void async16(const void* g, void* l) {
    __builtin_amdgcn_global_load_lds(
        (const __attribute__((address_space(1))) unsigned int*)g,
        (__attribute__((address_space(3))) unsigned int*)l, 16, 0, 0);
}

// ---------------------------------------------------------------------------
// Fused conversion kernel: x, Wq, Wk(->wqkv+2048*2048), Wv(->wqkv+2560*2048),
// Wo -> bf16; mask -> mask*log2e (fp32).
// ---------------------------------------------------------------------------
__global__ __launch_bounds__(256) void conv_all(
    const float* __restrict__ x,  const float* __restrict__ wq,
    const float* __restrict__ wk, const float* __restrict__ wv,
    const float* __restrict__ wo, const float* __restrict__ mask,
    unsigned short* __restrict__ xb, unsigned short* __restrict__ wqkvb,
    unsigned short* __restrict__ wob, float* __restrict__ maskL)
{
    int u = blockIdx.x * 256 + threadIdx.x;
    const float* s;
    unsigned short* d;
    if (u < 1048576)      { s = x  + (size_t)u * 8;             d = xb   + (size_t)u * 8; }
    else if (u < 1572864) { size_t t = (size_t)(u - 1048576) * 8; s = wq + t; d = wqkvb + t; }
    else if (u < 1703936) { size_t t = (size_t)(u - 1572864) * 8; s = wk + t; d = wqkvb + (size_t)2048 * 2048 + t; }
    else if (u < 1835008) { size_t t = (size_t)(u - 1703936) * 8; s = wv + t; d = wqkvb + (size_t)2560 * 2048 + t; }
    else if (u < 2359296) { size_t t = (size_t)(u - 1835008) * 8; s = wo + t; d = wob + t; }
    else if (u < 2359808) {
        int m = (u - 2359296) * 8;
        float4 a = *(const float4*)(mask + m);
        float4 b = *(const float4*)(mask + m + 4);
        float4 oa = {a.x * LOG2E, a.y * LOG2E, a.z * LOG2E, a.w * LOG2E};
        float4 ob = {b.x * LOG2E, b.y * LOG2E, b.z * LOG2E, b.w * LOG2E};
        *(float4*)(maskL + m) = oa;
        *(float4*)(maskL + m + 4) = ob;
        return;
    } else return;
    float4 a = *(const float4*)s;
    float4 b = *(const float4*)(s + 4);
    v8s o;
    o[0] = (short)f2bf(a.x); o[1] = (short)f2bf(a.y);
    o[2] = (short)f2bf(a.z); o[3] = (short)f2bf(a.w);
    o[4] = (short)f2bf(b.x); o[5] = (short)f2bf(b.y);
    o[6] = (short)f2bf(b.z); o[7] = (short)f2bf(b.w);
    *(v8s*)d = o;
}

// ---------------------------------------------------------------------------
// bf16 MFMA GEMM, triple-buffered async staging (prefetch distance 2,
// ONE barrier per K-iter). 128x128x32 tiles, 4 waves, 64x64/wave.
// MODE 0: fp32 out + bias + residual (O-proj).
// MODE 3: fused QKV; cols [0,2048) Q (scaled), [2048,2560) K, [2560,3072) V.
// ---------------------------------------------------------------------------
template <int MODE>
__global__ __launch_bounds__(256) void gemm_mfma(
    const unsigned short* __restrict__ A, const unsigned short* __restrict__ W,
    const float* __restrict__ b0, const float* __restrict__ b1,
    const float* __restrict__ b2,
    unsigned short* __restrict__ oq, unsigned short* __restrict__ ok,
    unsigned short* __restrict__ ov,
    float* __restrict__ of, const float* __restrict__ resid,
    int K, int N)
{
    __shared__ short SM[3 * 8192];   // per buf: A 4096 shorts | B 4096 shorts

    const int tid  = threadIdx.x;
    const int lane = tid & 63;
    const int wave = tid >> 6;
    const int lid  = lane & 15;
    const int g    = lane >> 4;
    const int wr   = wave >> 1, wc = wave & 1;
    const int row0 = blockIdx.y * 128, col0 = blockIdx.x * 128;

    auto stage = [&](int k0, int buf) {
#pragma unroll
        for (int i = 0; i < 2; ++i) {
            int idx = tid + i * 256;               // 0..511
            int r = idx >> 2, s = idx & 3;
            int c = s ^ ((r >> 1) & 3);
            async16(A + (size_t)(row0 + r) * K + k0 + c * 8,
                    &SM[buf * 8192 + idx * 8]);
            async16(W + (size_t)(col0 + r) * K + k0 + c * 8,
                    &SM[buf * 8192 + 4096 + idx * 8]);
        }
    };

    v4f acc[4][4];
#pragma unroll
    for (int i = 0; i < 4; ++i)
#pragma unroll
        for (int j = 0; j < 4; ++j) acc[i][j] = (v4f){0.f, 0.f, 0.f, 0.f};

    stage(0, 0);
    stage(32, 1);
    int p = 0;
    for (int k0 = 0; k0 < K; k0 += 32) {
        __syncthreads();
        if (k0 + 64 < K) {
            int nb = p + 2; if (nb >= 3) nb -= 3;
            stage(k0 + 64, nb);
        }
        const short* As = &SM[p * 8192];
        const short* Bs = &SM[p * 8192 + 4096];

        v8s af[4], bf[4];
#pragma unroll
        for (int t = 0; t < 4; ++t) {
            int ra = wr * 64 + t * 16 + lid;
            int rb = wc * 64 + t * 16 + lid;
            af[t] = *(const v8s*)&As[ra * 32 + ((g ^ ((ra >> 1) & 3)) * 8)];
            bf[t] = *(const v8s*)&Bs[rb * 32 + ((g ^ ((rb >> 1) & 3)) * 8)];
        }
#pragma unroll
        for (int mt = 0; mt < 4; ++mt)
#pragma unroll
            for (int nt = 0; nt < 4; ++nt)
                acc[mt][nt] = __builtin_amdgcn_mfma_f32_16x16x32_bf16(
                    af[mt], bf[nt], acc[mt][nt], 0, 0, 0);
        if (++p == 3) p = 0;
    }

    // epilogue: C/D layout col = lane&15, row = g*4 + reg
    const int crow = row0 + wr * 64, ccol = col0 + wc * 64;
    if (MODE == 0) {
#pragma unroll
        for (int mt = 0; mt < 4; ++mt)
#pragma unroll
            for (int nt = 0; nt < 4; ++nt) {
                int cc = ccol + nt * 16 + lid;
                float bb = b0[cc];
#pragma unroll
                for (int r = 0; r < 4; ++r) {
                    int rr = crow + mt * 16 + g * 4 + r;
                    of[(size_t)rr * N + cc] =
                        acc[mt][nt][r] + bb + resid[(size_t)rr * N + cc];
                }
            }
    } else {
        const int seg = (col0 < 2048) ? 0 : (col0 < 2560 ? 1 : 2);
#pragma unroll
        for (int mt = 0; mt < 4; ++mt)
#pragma unroll
            for (int nt = 0; nt < 4; ++nt) {
                int cc = ccol + nt * 16 + lid;
                if (seg == 0) {
                    float bb = b0[cc];
#pragma unroll
                    for (int r = 0; r < 4; ++r) {
                        int rr = crow + mt * 16 + g * 4 + r;
                        oq[(size_t)rr * 2048 + cc] =
                            f2bf((acc[mt][nt][r] + bb) * QSCALE);
                    }
                } else if (seg == 1) {
                    float bb = b1[cc - 2048];
#pragma unroll
                    for (int r = 0; r < 4; ++r) {
                        int rr = crow + mt * 16 + g * 4 + r;
                        ok[(size_t)rr * 512 + (cc - 2048)] =
                            f2bf(acc[mt][nt][r] + bb);
                    }
                } else {
                    float bb = b2[cc - 2560];
#pragma unroll
                    for (int r = 0; r < 4; ++r) {
                        int rr = crow + mt * 16 + g * 4 + r;
                        ov[(size_t)rr * 512 + (cc - 2560)] =
                            f2bf(acc[mt][nt][r] + bb);
                    }
                }
            }
    }
}

// ---------------------------------------------------------------------------
// V transpose: [4096][512] -> Vt[(b*512 + c)][2048], LDS-tiled 64x64.
// Columns of Vt are stored in PV k-slot order: within each 32-key tile,
// pos g*8+hi*4+r <- key hi*16+g*4+r (attention is key-order-independent;
// makes the flash PV B-fragment a single contiguous 16B read).
// ---------------------------------------------------------------------------
__global__ __launch_bounds__(256) void transpose_v(
    const unsigned short* __restrict__ V, unsigned short* __restrict__ Vt)
{
    __shared__ unsigned short T[64][72];
    const int r0 = blockIdx.y * 64;
    const int c0 = blockIdx.x * 64;
    const int tid = threadIdx.x;
    const int r = tid >> 3, c8 = (tid & 7) * 8;
#pragma unroll
    for (int h = 0; h < 2; ++h) {
        v8s val = *(const v8s*)&V[(size_t)(r0 + h * 32 + r) * 512 + c0 + c8];
#pragma unroll
        for (int e = 0; e < 8; ++e) T[c8 + e][h * 32 + r] = (unsigned short)val[e];
    }
    __syncthreads();
#pragma unroll
    for (int h = 0; h < 2; ++h) {
        int idx = tid + h * 256;
        int ci = idx >> 3, ch = (idx & 7) * 8;   // ch = output pos base (mult of 8)
        int t32 = ch & 32;                        // which 32-key tile (0 or 32)
        int gg  = (ch >> 3) & 3;                  // g field of the 8-run
        int kb  = t32 + gg * 4;                   // keys kb..kb+3 and kb+16..+19
        uint2 lo = *(const uint2*)&T[ci][kb];
        uint2 hi = *(const uint2*)&T[ci][kb + 16];
        union { uint4 u; v8s v; } o;
        o.u.x = lo.x; o.u.y = lo.y; o.u.z = hi.x; o.u.w = hi.y;
        int rr = r0 + ch;
        *(v8s*)&Vt[((size_t)((rr >> 11) * 512 + c0 + ci)) * 2048 + (rr & 2047)] = o.v;
    }
}

// ---------------------------------------------------------------------------
// MFMA flash attention v8b (GQA). NO LDS, NO barriers: K and V fragments are
// read global->register directly (K/V per (b,kvh) = 512 KB each, L2-resident;
// the 16 KB/iter tile is L1-resident and shared by all 4 waves of a block,
// which read IDENTICAL K/V addresses). Every wave free-runs; the 2 waves/SIMD
// (structural cap: 2048 waves total) hide each other's stalls without
// lockstep staging. Software prefetch: K(t+1) issued after QK(t) MFMAs,
// V(t+1) after PV(t) -- each has >600 cyc of independent work before use.
// v8b: s_setprio(1) wrapped around both MFMA clusters (T5; attn +4-7%).
//
// 1D grid 512, XCD-aware decode: xcd = bid&7 -> h in {2*xcd, 2*xcd+1}, so
// each XCD touches ONE kvh (K+Vt slices = 2 MB < 4 MB L2).
//
// Register-direct P: lane (lid,g) owns P[q=lid] for keys {g*4+r, 16+g*4+r}
// = A-fragment k-slots g*8+{0..7}; V B-fragment is one contiguous 16B read
// (Vt pre-permuted into k-slot order). Math identical to v6/v7.
// ---------------------------------------------------------------------------
__global__ __launch_bounds__(256, 2) void flash_mfma(
    const unsigned short* __restrict__ Q,   // [B*L, 2048] bf16, pre-scaled
    const unsigned short* __restrict__ K,   // [B*L, 512]  bf16
    const unsigned short* __restrict__ Vt,  // [(b*512+kvh*128+d)][2048] bf16, k-slot order
    const float* __restrict__ maskL,        // [B,L] fp32, pre-multiplied log2e
    unsigned short* __restrict__ AO)        // [B*L, 2048] bf16
{
    const int tid  = threadIdx.x;
    const int lane = tid & 63;
    const int wave = tid >> 6;              // 0..3
    const int lid  = lane & 15;
    const int g    = lane >> 4;

    // XCD-aware decode (hw round-robins linear id % 8)
    const int bid = blockIdx.x;
    const int xm  = bid & 7;
    const int r_  = bid >> 3;               // 0..63
    const int h   = xm * 2 + (r_ & 1);
    const int b   = (r_ >> 1) & 1;
    const int q0  = (r_ >> 2) * 128;
    const int kvh = h >> 2;
    const int wq  = wave * 32;

    const unsigned short* Kb = K  + ((size_t)b * L_) * 512 + kvh * 128;
    const unsigned short* Vb = Vt + ((size_t)(b * 512 + kvh * 128)) * 2048;
    const float*          mb = maskL + b * L_;

    // Q fragments: B-operand, lane n=q (lid), k = g*8+j within 32-chunk kc
    v8s bq[2][4];
    {
        const size_t base = ((size_t)(b * L_ + q0 + wq + lid)) * 2048 + h * 128;
#pragma unroll
        for (int qt = 0; qt < 2; ++qt)
#pragma unroll
            for (int kc = 0; kc < 4; ++kc)
                bq[qt][kc] = *(const v8s*)(Q + base + (size_t)qt * 16 * 2048 +
                                           kc * 32 + g * 8);
    }

    v4f oacc[2][8];
#pragma unroll
    for (int mt = 0; mt < 2; ++mt)
#pragma unroll
        for (int nt = 0; nt < 8; ++nt) oacc[mt][nt] = (v4f){0.f, 0.f, 0.f, 0.f};
    float lsm[2] = {0.f, 0.f};

    // preload tile 0 fragments (K: A-operand rows; V: k-slot-ordered cols)
    v8s ak[2][4], vv[8];
#pragma unroll
    for (int kt = 0; kt < 2; ++kt)
#pragma unroll
        for (int kc = 0; kc < 4; ++kc)
            ak[kt][kc] = *(const v8s*)(Kb + (size_t)(kt * 16 + lid) * 512 +
                                       kc * 32 + g * 8);
#pragma unroll
    for (int nt = 0; nt < 8; ++nt)
        vv[nt] = *(const v8s*)(Vb + (size_t)(nt * 16 + lid) * 2048 + g * 8);

    for (int it = 0; it < 64; ++it) {
        const int k0 = it * 32;

        // S^T = K x Q, accumulator seeded with mask (log2 domain):
        // D[k][q], lane q = qt*16+lid, k = kt*16 + g*4 + r
        v4f sacc[2][2];
#pragma unroll
        for (int kt = 0; kt < 2; ++kt) {
            float4 mk = *(const float4*)&mb[k0 + kt * 16 + g * 4];
            v4f seed = {mk.x, mk.y, mk.z, mk.w};
            sacc[kt][0] = seed;
            sacc[kt][1] = seed;
        }
        __builtin_amdgcn_s_setprio(1);
#pragma unroll
        for (int kc = 0; kc < 4; ++kc)
#pragma unroll
            for (int kt = 0; kt < 2; ++kt)
#pragma unroll
                for (int qt = 0; qt < 2; ++qt)
                    sacc[kt][qt] = __builtin_amdgcn_mfma_f32_16x16x32_bf16(
                        ak[kt][kc], bq[qt][kc], sacc[kt][qt], 0, 0, 0);
        __builtin_amdgcn_s_setprio(0);

        // prefetch K(t+1); sched_barrier keeps the new defs below the QK
        // MFMAs (avoids live-range doubling), while still allowing the
        // loads to interleave with the exp2 block below.
        __builtin_amdgcn_sched_barrier(0);
        if (it < 63) {
            const int kn = k0 + 32 + lid;
#pragma unroll
            for (int kt = 0; kt < 2; ++kt)
#pragma unroll
                for (int kc = 0; kc < 4; ++kc)
                    ak[kt][kc] = *(const v8s*)(Kb +
                        (size_t)(kn + kt * 16) * 512 + kc * 32 + g * 8);
        }

        // p = exp2(s); accumulate unnormalized row-sums; pack A-fragments
        // IN REGISTERS: k-slot g*8+j holds key (j>>2)*16 + g*4 + (j&3).
        v8s ap[2];
#pragma unroll
        for (int qt = 0; qt < 2; ++qt) {
            float e0 = __builtin_amdgcn_exp2f(sacc[0][qt][0]);
            float e1 = __builtin_amdgcn_exp2f(sacc[0][qt][1]);
            float e2 = __builtin_amdgcn_exp2f(sacc[0][qt][2]);
            float e3 = __builtin_amdgcn_exp2f(sacc[0][qt][3]);
            float f0 = __builtin_amdgcn_exp2f(sacc[1][qt][0]);
            float f1 = __builtin_amdgcn_exp2f(sacc[1][qt][1]);
            float f2 = __builtin_amdgcn_exp2f(sacc[1][qt][2]);
            float f3 = __builtin_amdgcn_exp2f(sacc[1][qt][3]);
            lsm[qt] += ((e0 + e1) + (e2 + e3)) + ((f0 + f1) + (f2 + f3));
            union { uint4 u; v8s v; } pa;
            pa.u.x = pk2bf(e0, e1);
            pa.u.y = pk2bf(e2, e3);
            pa.u.z = pk2bf(f0, f1);
            pa.u.w = pk2bf(f2, f3);
            ap[qt] = pa.v;
        }

        // P·V accumulate: B-fragment = vv[nt] (k-slot order, preloaded)
        __builtin_amdgcn_s_setprio(1);
#pragma unroll
        for (int nt = 0; nt < 8; ++nt)
#pragma unroll
            for (int mt = 0; mt < 2; ++mt)
                oacc[mt][nt] = __builtin_amdgcn_mfma_f32_16x16x32_bf16(
                    ap[mt], vv[nt], oacc[mt][nt], 0, 0, 0);
        __builtin_amdgcn_s_setprio(0);

        // prefetch V(t+1) (consumed after next iter's QK+exp2)
        __builtin_amdgcn_sched_barrier(0);
        if (it < 63) {
            const int cn = k0 + 32 + g * 8;
#pragma unroll
            for (int nt = 0; nt < 8; ++nt)
                vv[nt] = *(const v8s*)(Vb + (size_t)(nt * 16 + lid) * 2048 + cn);
        }
    }

    // reduce l across the 4 lane-groups (same q-row), normalize, store
#pragma unroll
    for (int qt = 0; qt < 2; ++qt) {
        lsm[qt] += __shfl_xor(lsm[qt], 16);
        lsm[qt] += __shfl_xor(lsm[qt], 32);
    }
#pragma unroll
    for (int mt = 0; mt < 2; ++mt) {
        float linv[4];
#pragma unroll
        for (int r = 0; r < 4; ++r) linv[r] = 1.0f / __shfl(lsm[mt], g * 4 + r);
#pragma unroll
        for (int nt = 0; nt < 8; ++nt)
#pragma unroll
            for (int r = 0; r < 4; ++r) {
                size_t orow = (size_t)(b * L_ + q0 + wq + mt * 16 + g * 4 + r);
                AO[orow * 2048 + h * 128 + nt * 16 + lid] =
                    f2bf(oacc[mt][nt][r] * linv[r]);
            }
    }
}

// ---------------------------------------------------------------------------
// LayerNorm over rows of P (P = proj + bias + residual already).
// ---------------------------------------------------------------------------
__global__ __launch_bounds__(256) void ln_kernel(
    const float* __restrict__ P, const float* __restrict__ g,
    const float* __restrict__ bta, float* __restrict__ Out)
{
    const int row = blockIdx.x;
    const int tid = threadIdx.x;
    const float* p = P + (size_t)row * H_;

    float vals[8];
    float s = 0.f;
#pragma unroll
    for (int it = 0; it < 2; ++it) {
        int c = tid * 4 + it * 1024;
        float4 a = *(const float4*)&p[c];
        vals[it * 4 + 0] = a.x; vals[it * 4 + 1] = a.y;
        vals[it * 4 + 2] = a.z; vals[it * 4 + 3] = a.w;
        s += a.x + a.y + a.z + a.w;
    }
    __shared__ float red[4];
    float t = s;
#pragma unroll
    for (int off = 32; off > 0; off >>= 1) t += __shfl_xor(t, off);
    if ((tid & 63) == 0) red[tid >> 6] = t;
    __syncthreads();
    float mean = (red[0] + red[1] + red[2] + red[3]) * (1.f / (float)H_);

    float vsum = 0.f;
#pragma unroll
    for (int i = 0; i < 8; ++i) {
        float d = vals[i] - mean;
        vsum += d * d;
    }
    __syncthreads();
    t = vsum;
#pragma unroll
    for (int off = 32; off > 0; off >>= 1) t += __shfl_xor(t, off);
    if ((tid & 63) == 0) red[tid >> 6] = t;
    __syncthreads();
    float var = (red[0] + red[1] + red[2] + red[3]) * (1.f / (float)H_);
    float rs  = 1.f / sqrtf(var + 1e-12f);

#pragma unroll
    for (int it = 0; it < 2; ++it) {
        int c = tid * 4 + it * 1024;
        float4 gv = *(const float4*)&g[c];
        float4 bv = *(const float4*)&bta[c];
        float4 ov;
        ov.x = (vals[it * 4 + 0] - mean) * rs * gv.x + bv.x;
        ov.y = (vals[it * 4 + 1] - mean) * rs * gv.y + bv.y;
        ov.z = (vals[it * 4 + 2] - mean) * rs * gv.z + bv.z;
        ov.w = (vals[it * 4 + 3] - mean) * rs * gv.w + bv.w;
        *(float4*)&Out[(size_t)row * H_ + c] = ov;
    }
}

// ---------------------------------------------------------------------------
extern "C" void kernel_launch(void* const* d_in, const int* in_sizes, int n_in,
                              void* d_out, int out_size, void* d_ws, size_t ws_size,
                              hipStream_t stream)
{
    const float* x    = (const float*)d_in[0];
    const float* mask = (const float*)d_in[1];
    const float* Wq   = (const float*)d_in[2];
    const float* bq   = (const float*)d_in[3];
    const float* Wk   = (const float*)d_in[4];
    const float* bk   = (const float*)d_in[5];
    const float* Wv   = (const float*)d_in[6];
    const float* bv   = (const float*)d_in[7];
    const float* Wo   = (const float*)d_in[8];
    const float* bo   = (const float*)d_in[9];
    const float* lng  = (const float*)d_in[10];
    const float* lnb  = (const float*)d_in[11];
    float* out = (float*)d_out;

    char* ws = (char*)d_ws;
    unsigned short* xb    = (unsigned short*)(ws);              // 16.78 MB
    unsigned short* wqkv  = (unsigned short*)(ws + 16777216);   // 12.58 MB
    float*          maskL = (float*)         (ws + 29360128);   // 16 KB
    unsigned short* q     = (unsigned short*)(ws + 29376512);   // 16.78 MB
    unsigned short* k     = (unsigned short*)(ws + 46153728);   //  4.19 MB
    unsigned short* vnat  = (unsigned short*)(ws + 50348032);   //  4.19 MB
    unsigned short* vt    = (unsigned short*)(ws + 54542336);   //  4.19 MB
    unsigned short* ao    = (unsigned short*)(ws + 58736640);   // 16.78 MB
    unsigned short* wob   = (unsigned short*)(ws + 75513856);   //  8.39 MB
    float*          pj    = (float*)(ws);                       // 33.55 MB,
                                        // reuses xb/wqkv/maskL/q-head (dead)

    dim3 blk(256);
    // fused conversions (x, Wq, Wk, Wv, Wo, mask*log2e)
    conv_all<<<9218, blk, 0, stream>>>(x, Wq, Wk, Wv, Wo, mask,
                                       xb, wqkv, wob, maskL);

    // fused QKV projection (Q pre-scaled; V natural layout)
    gemm_mfma<3><<<dim3(24, 32), blk, 0, stream>>>(
        xb, wqkv, bq, bk, bv, q, k, vnat, nullptr, nullptr, 2048, 3072);

    // V transpose (k-slot-permuted columns) for flash
    transpose_v<<<dim3(8, 64), blk, 0, stream>>>(vnat, vt);

    // attention: barrier-free, LDS-free, global->reg K/V; 1D grid 512,
    // XCD-aware decode inside the kernel
    flash_mfma<<<dim3(512), dim3(256), 0, stream>>>(q, k, vt, maskL, ao);

    // output projection + bias + residual, then layernorm
    gemm_mfma<0><<<dim3(16, 32), blk, 0, stream>>>(
        ao, wob, bo, nullptr, nullptr, nullptr, nullptr, nullptr, pj, x, 2048, 2048);
    ln_kernel<<<4096, blk, 0, stream>>>(pj, lng, lnb, out);
}

// Round 7
// 342.955 us; speedup vs baseline: 1.4131x; 1.4131x over previous
//
#include <hip/hip_runtime.h>
#include <math.h>

typedef short v8s __attribute__((ext_vector_type(8)));
typedef short v4s __attribute__((ext_vector_type(4)));
typedef float v4f __attribute__((ext_vector_type(4)));
typedef unsigned long long ull;

constexpr int L_ = 2048;
constexpr int H_ = 2048;
constexpr float LOG2E = 1.4426950408889634f;
constexpr float QSCALE = 0.08838834764831845f * LOG2E; // 1/sqrt(128) * log2(e)

__device__ inline unsigned short f2bf(float f) {
    unsigned int u = __float_as_uint(f);
    u += 0x7fffu + ((u >> 16) & 1u);
    return (unsigned short)(u >> 16);
}

// pack two fp32 -> two bf16 in one u32 (round-half-up): 2 adds + 1 v_perm
__device__ inline unsigned int pk2bf(float lo, float hi) {
    unsigned int a = __float_as_uint(lo) + 0x8000u;
    unsigned int b = __float_as_uint(hi) + 0x8000u;
    return __builtin_amdgcn_perm(b, a, 0x07060302);  // {hi16(b), hi16(a)}
}

// async global->LDS, 16 bytes per lane; LDS dest = uniform base + lane*16B
__device__ inline void async16(const void* g, void* l) {
    __builtin_amdgcn_global_load_lds(
        (const __attribute__((address_space(1))) unsigned int*)g,
        (__attribute__((address_space(3))) unsigned int*)l, 16, 0, 0);
}

// ---------------------------------------------------------------------------
// Fused conversion kernel: x, Wq, Wk(->wqkv+2048*2048), Wv(->wqkv+2560*2048),
// Wo -> bf16; mask -> mask*log2e (fp32).
// ---------------------------------------------------------------------------
__global__ __launch_bounds__(256) void conv_all(
    const float* __restrict__ x,  const float* __restrict__ wq,
    const float* __restrict__ wk, const float* __restrict__ wv,
    const float* __restrict__ wo, const float* __restrict__ mask,
    unsigned short* __restrict__ xb, unsigned short* __restrict__ wqkvb,
    unsigned short* __restrict__ wob, float* __restrict__ maskL)
{
    int u = blockIdx.x * 256 + threadIdx.x;
    const float* s;
    unsigned short* d;
    if (u < 1048576)      { s = x  + (size_t)u * 8;             d = xb   + (size_t)u * 8; }
    else if (u < 1572864) { size_t t = (size_t)(u - 1048576) * 8; s = wq + t; d = wqkvb + t; }
    else if (u < 1703936) { size_t t = (size_t)(u - 1572864) * 8; s = wk + t; d = wqkvb + (size_t)2048 * 2048 + t; }
    else if (u < 1835008) { size_t t = (size_t)(u - 1703936) * 8; s = wv + t; d = wqkvb + (size_t)2560 * 2048 + t; }
    else if (u < 2359296) { size_t t = (size_t)(u - 1835008) * 8; s = wo + t; d = wob + t; }
    else if (u < 2359808) {
        int m = (u - 2359296) * 8;
        float4 a = *(const float4*)(mask + m);
        float4 b = *(const float4*)(mask + m + 4);
        float4 oa = {a.x * LOG2E, a.y * LOG2E, a.z * LOG2E, a.w * LOG2E};
        float4 ob = {b.x * LOG2E, b.y * LOG2E, b.z * LOG2E, b.w * LOG2E};
        *(float4*)(maskL + m) = oa;
        *(float4*)(maskL + m + 4) = ob;
        return;
    } else return;
    float4 a = *(const float4*)s;
    float4 b = *(const float4*)(s + 4);
    v8s o;
    o[0] = (short)f2bf(a.x); o[1] = (short)f2bf(a.y);
    o[2] = (short)f2bf(a.z); o[3] = (short)f2bf(a.w);
    o[4] = (short)f2bf(b.x); o[5] = (short)f2bf(b.y);
    o[6] = (short)f2bf(b.z); o[7] = (short)f2bf(b.w);
    *(v8s*)d = o;
}

// ---------------------------------------------------------------------------
// bf16 MFMA GEMM, triple-buffered async staging (prefetch distance 2,
// ONE barrier per K-iter). 128x128x32 tiles, 4 waves, 64x64/wave.
// MODE 0: fp32 out + bias + residual (O-proj).
// MODE 3: fused QKV; cols [0,2048) Q (scaled), [2048,2560) K natural,
//         [2560,3072) V written DIRECTLY into Vt (transposed + k-slot
//         permuted for flash; replaces the old transpose_v kernel).
//         Vt[row][col]: row = b*512 + d' (d'=cc-2560), col = within-batch
//         key l at permuted pos: (crow&2047) + (mt>>1)*32 + g*8 + (mt&1)*4
//         + r  (key w = hi*16+g*4+r -> pos g*8+hi*4+r, hi=mt&1).
// ---------------------------------------------------------------------------
template <int MODE>
__global__ __launch_bounds__(256) void gemm_mfma(
    const unsigned short* __restrict__ A, const unsigned short* __restrict__ W,
    const float* __restrict__ b0, const float* __restrict__ b1,
    const float* __restrict__ b2,
    unsigned short* __restrict__ oq, unsigned short* __restrict__ ok,
    unsigned short* __restrict__ ov,
    float* __restrict__ of, const float* __restrict__ resid,
    int K, int N)
{
    __shared__ short SM[3 * 8192];   // per buf: A 4096 shorts | B 4096 shorts

    const int tid  = threadIdx.x;
    const int lane = tid & 63;
    const int wave = tid >> 6;
    const int lid  = lane & 15;
    const int g    = lane >> 4;
    const int wr   = wave >> 1, wc = wave & 1;
    const int row0 = blockIdx.y * 128, col0 = blockIdx.x * 128;

    auto stage = [&](int k0, int buf) {
#pragma unroll
        for (int i = 0; i < 2; ++i) {
            int idx = tid + i * 256;               // 0..511
            int r = idx >> 2, s = idx & 3;
            int c = s ^ ((r >> 1) & 3);
            async16(A + (size_t)(row0 + r) * K + k0 + c * 8,
                    &SM[buf * 8192 + idx * 8]);
            async16(W + (size_t)(col0 + r) * K + k0 + c * 8,
                    &SM[buf * 8192 + 4096 + idx * 8]);
        }
    };

    v4f acc[4][4];
#pragma unroll
    for (int i = 0; i < 4; ++i)
#pragma unroll
        for (int j = 0; j < 4; ++j) acc[i][j] = (v4f){0.f, 0.f, 0.f, 0.f};

    stage(0, 0);
    stage(32, 1);
    int p = 0;
    for (int k0 = 0; k0 < K; k0 += 32) {
        __syncthreads();
        if (k0 + 64 < K) {
            int nb = p + 2; if (nb >= 3) nb -= 3;
            stage(k0 + 64, nb);
        }
        const short* As = &SM[p * 8192];
        const short* Bs = &SM[p * 8192 + 4096];

        v8s af[4], bf[4];
#pragma unroll
        for (int t = 0; t < 4; ++t) {
            int ra = wr * 64 + t * 16 + lid;
            int rb = wc * 64 + t * 16 + lid;
            af[t] = *(const v8s*)&As[ra * 32 + ((g ^ ((ra >> 1) & 3)) * 8)];
            bf[t] = *(const v8s*)&Bs[rb * 32 + ((g ^ ((rb >> 1) & 3)) * 8)];
        }
#pragma unroll
        for (int mt = 0; mt < 4; ++mt)
#pragma unroll
            for (int nt = 0; nt < 4; ++nt)
                acc[mt][nt] = __builtin_amdgcn_mfma_f32_16x16x32_bf16(
                    af[mt], bf[nt], acc[mt][nt], 0, 0, 0);
        if (++p == 3) p = 0;
    }

    // epilogue: C/D layout col = lane&15, row = g*4 + reg
    const int crow = row0 + wr * 64, ccol = col0 + wc * 64;
    if (MODE == 0) {
#pragma unroll
        for (int mt = 0; mt < 4; ++mt)
#pragma unroll
            for (int nt = 0; nt < 4; ++nt) {
                int cc = ccol + nt * 16 + lid;
                float bb = b0[cc];
#pragma unroll
                for (int r = 0; r < 4; ++r) {
                    int rr = crow + mt * 16 + g * 4 + r;
                    of[(size_t)rr * N + cc] =
                        acc[mt][nt][r] + bb + resid[(size_t)rr * N + cc];
                }
            }
    } else {
        const int seg = (col0 < 2048) ? 0 : (col0 < 2560 ? 1 : 2);
#pragma unroll
        for (int mt = 0; mt < 4; ++mt)
#pragma unroll
            for (int nt = 0; nt < 4; ++nt) {
                int cc = ccol + nt * 16 + lid;
                if (seg == 0) {
                    float bb = b0[cc];
#pragma unroll
                    for (int r = 0; r < 4; ++r) {
                        int rr = crow + mt * 16 + g * 4 + r;
                        oq[(size_t)rr * 2048 + cc] =
                            f2bf((acc[mt][nt][r] + bb) * QSCALE);
                    }
                } else if (seg == 1) {
                    float bb = b1[cc - 2048];
#pragma unroll
                    for (int r = 0; r < 4; ++r) {
                        int rr = crow + mt * 16 + g * 4 + r;
                        ok[(size_t)rr * 512 + (cc - 2048)] =
                            f2bf(acc[mt][nt][r] + bb);
                    }
                } else {
                    // V -> Vt directly (transposed + k-slot permuted),
                    // bit-identical f2bf, one 8B store per (mt,nt).
                    float bb = b2[cc - 2560];
                    int dprime = cc - 2560;                       // 0..511
                    int colb = (crow & 2047) + ((mt >> 1) << 5) +
                               (g << 3) + ((mt & 1) << 2);
                    size_t vrow = (size_t)((crow >> 11) * 512 + dprime);
                    unsigned int lo =
                        (unsigned int)f2bf(acc[mt][nt][0] + bb) |
                        ((unsigned int)f2bf(acc[mt][nt][1] + bb) << 16);
                    unsigned int hi =
                        (unsigned int)f2bf(acc[mt][nt][2] + bb) |
                        ((unsigned int)f2bf(acc[mt][nt][3] + bb) << 16);
                    uint2 pkv; pkv.x = lo; pkv.y = hi;
                    *(uint2*)&ov[vrow * 2048 + colb] = pkv;
                }
            }
    }
}

// ---------------------------------------------------------------------------
// MFMA flash attention v9 (GQA). v6's verified math at v4's measured-best
// block shape + v8's validated XCD pinning:
//   * 512 threads (8 waves), 256 q-rows/block, grid 256 = 1 block/CU.
//   * K/V double-buffered via global_load_lds (coalesced, once per BLOCK --
//     v8 showed direct global->reg strided reads are TA/L1-bound, 2.2x worse).
//   * ONE __syncthreads per 32-key iter (v4/v6 scheme).
//   * XCD decode: bid&7 -> (kvh,b), so each XCD's L2 holds exactly one
//     1 MB K+Vt slice (v8 measured FETCH 41->16.5 MB with this pinning).
//   * Register-direct P (no P_s): lane (lid,g) owns P[q] for keys
//     {g*4+r, 16+g*4+r} = A-fragment k-slots g*8+{0..7}; V B-fragment is one
//     contiguous ds_read_b128 (Vt pre-permuted into k-slot order by the QKV
//     GEMM epilogue). Math identical to v6/v7 (verified passing).
// ---------------------------------------------------------------------------
__global__ __launch_bounds__(512) void flash_mfma(
    const unsigned short* __restrict__ Q,   // [B*L, 2048] bf16, pre-scaled
    const unsigned short* __restrict__ K,   // [B*L, 512]  bf16
    const unsigned short* __restrict__ Vt,  // [(b*512+kvh*128+d)][2048] bf16, k-slot order
    const float* __restrict__ maskL,        // [B,L] fp32, pre-multiplied log2e
    unsigned short* __restrict__ AO)        // [B*L, 2048] bf16
{
    __shared__ short K_s[2][32 * 128];      // [buf][32 keys][16 chunks of 8]
    __shared__ short V_s[2][128 * 32];      // [buf][128 d][4 chunks of 8 pos]

    const int tid  = threadIdx.x;
    const int lane = tid & 63;
    const int wave = tid >> 6;              // 0..7
    const int lid  = lane & 15;
    const int g    = lane >> 4;
    const int lh   = (lid >> 2) & 3;

    // XCD-aware decode: hw round-robins linear bid % 8 across XCDs.
    const int c7   = blockIdx.x & 7;
    const int kvh  = c7 >> 1;
    const int b    = c7 & 1;
    const int rest = blockIdx.x >> 3;       // 0..31
    const int h    = kvh * 4 + (rest & 3);
    const int q0   = (rest >> 2) * 256;     // 0..1792
    const int wq   = wave * 32;

    // staging pointers: 512 threads cover the 512 16B chunks of each array.
    const unsigned short* pK;
    const unsigned short* pV;
    {
        int kr = tid >> 4, ks = tid & 15;   // kr 0..31
        pK = K + ((size_t)(b * L_ + kr)) * 512 + kvh * 128 +
             ((ks ^ (kr & 15)) * 8);
        int vd = tid >> 2, vs = tid & 3;    // vd 0..127
        pV = Vt + ((size_t)(b * 512 + kvh * 128 + vd)) * 2048 +
             ((vs ^ ((vd >> 2) & 3)) * 8);
    }

    // Q fragments: B-operand, lane n=q (lid), k = g*8+j within 32-chunk kc
    v8s bq[2][4];
    {
        const size_t base = ((size_t)(b * L_ + q0 + wq + lid)) * 2048 + h * 128;
#pragma unroll
        for (int qt = 0; qt < 2; ++qt)
#pragma unroll
            for (int kc = 0; kc < 4; ++kc)
                bq[qt][kc] = *(const v8s*)(Q + base + (size_t)qt * 16 * 2048 +
                                           kc * 32 + g * 8);
    }

    v4f oacc[2][8];
#pragma unroll
    for (int mt = 0; mt < 2; ++mt)
#pragma unroll
        for (int nt = 0; nt < 8; ++nt) oacc[mt][nt] = (v4f){0.f, 0.f, 0.f, 0.f};
    float lsm[2] = {0.f, 0.f};

    // prologue stage into buf 0
    async16(pK, &K_s[0][tid * 8]);
    async16(pV, &V_s[0][tid * 8]);

    for (int it = 0; it < 64; ++it) {
        const int p = it & 1;
        const int k0 = it * 32;
        __syncthreads();                    // drains buf[p]; guards buf[p^1]
        pK += 32 * 512;                     // next 32 keys
        pV += 32;                           // next 32 positions
        if (it + 1 < 64) {
            async16(pK, &K_s[p ^ 1][tid * 8]);
            async16(pV, &V_s[p ^ 1][tid * 8]);
        }
        const short* Ks = K_s[p];
        const short* Vs = V_s[p];

        // S^T = K x Q, accumulator seeded with mask (log2 domain):
        // D[k][q], lane q = qt*16+lid, k = kt*16 + g*4 + r
        v4f sacc[2][2];
#pragma unroll
        for (int kt = 0; kt < 2; ++kt) {
            float4 mk = *(const float4*)&maskL[b * L_ + k0 + kt * 16 + g * 4];
            v4f seed = {mk.x, mk.y, mk.z, mk.w};
            sacc[kt][0] = seed;
            sacc[kt][1] = seed;
        }
#pragma unroll
        for (int kc = 0; kc < 4; ++kc)
#pragma unroll
            for (int kt = 0; kt < 2; ++kt) {
                v8s ak = *(const v8s*)&Ks[(kt * 16 + lid) * 128 +
                                          (((kc * 4 + g) ^ lid) * 8)];
#pragma unroll
                for (int qt = 0; qt < 2; ++qt)
                    sacc[kt][qt] = __builtin_amdgcn_mfma_f32_16x16x32_bf16(
                        ak, bq[qt][kc], sacc[kt][qt], 0, 0, 0);
            }

        // p = exp2(s); accumulate unnormalized row-sums; pack A-fragments
        // IN REGISTERS: k-slot g*8+j holds key (j>>2)*16 + g*4 + (j&3).
        v8s ap[2];
#pragma unroll
        for (int qt = 0; qt < 2; ++qt) {
            float e0 = __builtin_amdgcn_exp2f(sacc[0][qt][0]);
            float e1 = __builtin_amdgcn_exp2f(sacc[0][qt][1]);
            float e2 = __builtin_amdgcn_exp2f(sacc[0][qt][2]);
            float e3 = __builtin_amdgcn_exp2f(sacc[0][qt][3]);
            float f0 = __builtin_amdgcn_exp2f(sacc[1][qt][0]);
            float f1 = __builtin_amdgcn_exp2f(sacc[1][qt][1]);
            float f2 = __builtin_amdgcn_exp2f(sacc[1][qt][2]);
            float f3 = __builtin_amdgcn_exp2f(sacc[1][qt][3]);
            lsm[qt] += ((e0 + e1) + (e2 + e3)) + ((f0 + f1) + (f2 + f3));
            union { uint4 u; v8s v; } pa;
            pa.u.x = pk2bf(e0, e1);
            pa.u.y = pk2bf(e2, e3);
            pa.u.z = pk2bf(f0, f1);
            pa.u.w = pk2bf(f2, f3);
            ap[qt] = pa.v;
        }

        // P·V accumulate: B-fragment = one contiguous b128 per nt
        // (Vs row d holds 32 positions in k-slot order, XOR-swizzled).
#pragma unroll
        for (int nt = 0; nt < 8; ++nt) {
            v8s bv = *(const v8s*)&Vs[(nt * 16 + lid) * 32 + ((g ^ lh) * 8)];
#pragma unroll
            for (int mt = 0; mt < 2; ++mt)
                oacc[mt][nt] = __builtin_amdgcn_mfma_f32_16x16x32_bf16(
                    ap[mt], bv, oacc[mt][nt], 0, 0, 0);
        }
    }

    // reduce l across the 4 lane-groups (same q-row), normalize, store
#pragma unroll
    for (int qt = 0; qt < 2; ++qt) {
        lsm[qt] += __shfl_xor(lsm[qt], 16);
        lsm[qt] += __shfl_xor(lsm[qt], 32);
    }
#pragma unroll
    for (int mt = 0; mt < 2; ++mt) {
        float linv[4];
#pragma unroll
        for (int r = 0; r < 4; ++r) linv[r] = 1.0f / __shfl(lsm[mt], g * 4 + r);
#pragma unroll
        for (int nt = 0; nt < 8; ++nt)
#pragma unroll
            for (int r = 0; r < 4; ++r) {
                size_t orow = (size_t)(b * L_ + q0 + wq + mt * 16 + g * 4 + r);
                AO[orow * 2048 + h * 128 + nt * 16 + lid] =
                    f2bf(oacc[mt][nt][r] * linv[r]);
            }
    }
}

// ---------------------------------------------------------------------------
// LayerNorm over rows of P (P = proj + bias + residual already).
// ---------------------------------------------------------------------------
__global__ __launch_bounds__(256) void ln_kernel(
    const float* __restrict__ P, const float* __restrict__ g,
    const float* __restrict__ bta, float* __restrict__ Out)
{
    const int row = blockIdx.x;
    const int tid = threadIdx.x;
    const float* p = P + (size_t)row * H_;

    float vals[8];
    float s = 0.f;
#pragma unroll
    for (int it = 0; it < 2; ++it) {
        int c = tid * 4 + it * 1024;
        float4 a = *(const float4*)&p[c];
        vals[it * 4 + 0] = a.x; vals[it * 4 + 1] = a.y;
        vals[it * 4 + 2] = a.z; vals[it * 4 + 3] = a.w;
        s += a.x + a.y + a.z + a.w;
    }
    __shared__ float red[4];
    float t = s;
#pragma unroll
    for (int off = 32; off > 0; off >>= 1) t += __shfl_xor(t, off);
    if ((tid & 63) == 0) red[tid >> 6] = t;
    __syncthreads();
    float mean = (red[0] + red[1] + red[2] + red[3]) * (1.f / (float)H_);

    float vsum = 0.f;
#pragma unroll
    for (int i = 0; i < 8; ++i) {
        float d = vals[i] - mean;
        vsum += d * d;
    }
    __syncthreads();
    t = vsum;
#pragma unroll
    for (int off = 32; off > 0; off >>= 1) t += __shfl_xor(t, off);
    if ((tid & 63) == 0) red[tid >> 6] = t;
    __syncthreads();
    float var = (red[0] + red[1] + red[2] + red[3]) * (1.f / (float)H_);
    float rs  = 1.f / sqrtf(var + 1e-12f);

#pragma unroll
    for (int it = 0; it < 2; ++it) {
        int c = tid * 4 + it * 1024;
        float4 gv = *(const float4*)&g[c];
        float4 bv = *(const float4*)&bta[c];
        float4 ov;
        ov.x = (vals[it * 4 + 0] - mean) * rs * gv.x + bv.x;
        ov.y = (vals[it * 4 + 1] - mean) * rs * gv.y + bv.y;
        ov.z = (vals[it * 4 + 2] - mean) * rs * gv.z + bv.z;
        ov.w = (vals[it * 4 + 3] - mean) * rs * gv.w + bv.w;
        *(float4*)&Out[(size_t)row * H_ + c] = ov;
    }
}

// ---------------------------------------------------------------------------
extern "C" void kernel_launch(void* const* d_in, const int* in_sizes, int n_in,
                              void* d_out, int out_size, void* d_ws, size_t ws_size,
                              hipStream_t stream)
{
    const float* x    = (const float*)d_in[0];
    const float* mask = (const float*)d_in[1];
    const float* Wq   = (const float*)d_in[2];
    const float* bq   = (const float*)d_in[3];
    const float* Wk   = (const float*)d_in[4];
    const float* bk   = (const float*)d_in[5];
    const float* Wv   = (const float*)d_in[6];
    const float* bv   = (const float*)d_in[7];
    const float* Wo   = (const float*)d_in[8];
    const float* bo   = (const float*)d_in[9];
    const float* lng  = (const float*)d_in[10];
    const float* lnb  = (const float*)d_in[11];
    float* out = (float*)d_out;

    char* ws = (char*)d_ws;
    unsigned short* xb    = (unsigned short*)(ws);              // 16.78 MB
    unsigned short* wqkv  = (unsigned short*)(ws + 16777216);   // 12.58 MB
    float*          maskL = (float*)         (ws + 29360128);   // 16 KB
    unsigned short* q     = (unsigned short*)(ws + 29376512);   // 16.78 MB
    unsigned short* k     = (unsigned short*)(ws + 46153728);   //  4.19 MB
    unsigned short* vt    = (unsigned short*)(ws + 54542336);   //  4.19 MB
    unsigned short* ao    = (unsigned short*)(ws + 58736640);   // 16.78 MB
    unsigned short* wob   = (unsigned short*)(ws + 75513856);   //  8.39 MB
    float*          pj    = (float*)(ws);                       // 33.55 MB,
                                        // reuses xb/wqkv/maskL/q-head (dead)

    dim3 blk(256);
    // fused conversions (x, Wq, Wk, Wv, Wo, mask*log2e)
    conv_all<<<9218, blk, 0, stream>>>(x, Wq, Wk, Wv, Wo, mask,
                                       xb, wqkv, wob, maskL);

    // fused QKV projection (Q pre-scaled; K natural; V -> Vt directly)
    gemm_mfma<3><<<dim3(24, 32), blk, 0, stream>>>(
        xb, wqkv, bq, bk, bv, q, k, vt, nullptr, nullptr, 2048, 3072);

    // attention: 256 q-rows/block, 512 threads, grid 256 (1 block/CU),
    // XCD-pinned K/V slices
    flash_mfma<<<dim3(256), dim3(512), 0, stream>>>(q, k, vt, maskL, ao);

    // output projection + bias + residual, then layernorm
    gemm_mfma<0><<<dim3(16, 32), blk, 0, stream>>>(
        ao, wob, bo, nullptr, nullptr, nullptr, nullptr, nullptr, pj, x, 2048, 2048);
    ln_kernel<<<4096, blk, 0, stream>>>(pj, lng, lnb, out);
}